// Round 3
// baseline (414.333 us; speedup 1.0000x reference)
//
#include <hip/hip_runtime.h>
#include <hip/hip_bf16.h>
#include <cstdint>

// ---------- types ----------
typedef __attribute__((ext_vector_type(8))) __bf16 bf16x8;
typedef __attribute__((ext_vector_type(4))) float  f32x4;

// float -> bf16 round-to-nearest-even
__device__ __forceinline__ unsigned short f2bf(float x) {
    union { float f; unsigned u; } v; v.f = x;
    unsigned r = v.u + 0x7fffu + ((v.u >> 16) & 1u);
    return (unsigned short)(r >> 16);
}

__device__ __forceinline__ void gld_lds16(const unsigned short* g, unsigned short* l) {
    __builtin_amdgcn_global_load_lds(
        (const __attribute__((address_space(1))) unsigned int*)g,
        (__attribute__((address_space(3))) unsigned int*)l,
        16, 0, 0);
}

// ---------- P0: fp32 -> bf16 convert ----------
__global__ void cvt_kernel(const float* __restrict__ in, unsigned short* __restrict__ out, int n4) {
    int i = blockIdx.x * blockDim.x + threadIdx.x;
    if (i < n4) {
        float4 f = ((const float4*)in)[i];
        ushort4 o;
        o.x = f2bf(f.x); o.y = f2bf(f.y); o.z = f2bf(f.z); o.w = f2bf(f.w);
        ((ushort4*)out)[i] = o;
    }
}

// ---------- P1: transpose-convert 1024x1024 fp32 W[k][n] -> bf16 out[n][k] ----------
__global__ void wtrans_kernel(const float* __restrict__ W, unsigned short* __restrict__ out) {
    __shared__ float tile[32][33];
    int bx = blockIdx.x;          // k tile
    int by = blockIdx.y;          // n tile
    int tx = threadIdx.x;         // 0..31
    int ty = threadIdx.y;         // 0..7
#pragma unroll
    for (int j = 0; j < 4; j++)
        tile[ty + j*8][tx] = W[(size_t)(bx*32 + ty + j*8) * 1024 + by*32 + tx];
    __syncthreads();
#pragma unroll
    for (int j = 0; j < 4; j++)
        out[(size_t)(by*32 + ty + j*8) * 1024 + bx*32 + tx] = f2bf(tile[tx][ty + j*8]);
}

// ---------- P2: transpose V (bf16): VT[b][n][m] = QKV[b*2048+m][2048+n] ----------
__global__ void vtrans_kernel(const unsigned short* __restrict__ qkv, unsigned short* __restrict__ vt) {
    __shared__ unsigned short tile[32][33];
    int b = blockIdx.z;
    const unsigned short* V = qkv + (size_t)b * 2048 * 3072 + 2048;
    unsigned short* out = vt + (size_t)b * 1024 * 2048;
    int bx = blockIdx.x;          // m tile (64 tiles)
    int by = blockIdx.y;          // n tile (32 tiles)
    int tx = threadIdx.x, ty = threadIdx.y;
#pragma unroll
    for (int j = 0; j < 4; j++)
        tile[ty + j*8][tx] = V[(size_t)(bx*32 + ty + j*8) * 3072 + by*32 + tx];
    __syncthreads();
#pragma unroll
    for (int j = 0; j < 4; j++)
        out[(size_t)(by*32 + ty + j*8) * 2048 + bx*32 + tx] = tile[tx][ty + j*8];
}

// ---------- softmax: one block per row of 2048 bf16, in place ----------
__global__ void softmax_kernel(unsigned short* __restrict__ S) {
    const size_t row = blockIdx.x;
    unsigned short* p = S + row * 2048;
    const int tid = threadIdx.x;
    const int wave = tid >> 6, lane = tid & 63;

    uint4 raw = ((const uint4*)p)[tid];   // 8 bf16 per thread
    unsigned u[4] = {raw.x, raw.y, raw.z, raw.w};
    float x[8];
#pragma unroll
    for (int i = 0; i < 4; i++) {
        x[2*i]   = __uint_as_float(u[i] << 16);
        x[2*i+1] = __uint_as_float(u[i] & 0xffff0000u);
    }
    float m = x[0];
#pragma unroll
    for (int i = 1; i < 8; i++) m = fmaxf(m, x[i]);
#pragma unroll
    for (int off = 32; off >= 1; off >>= 1) m = fmaxf(m, __shfl_xor(m, off, 64));
    __shared__ float sm[4], ss[4];
    if (lane == 0) sm[wave] = m;
    __syncthreads();
    m = fmaxf(fmaxf(sm[0], sm[1]), fmaxf(sm[2], sm[3]));

    float e[8], s = 0.f;
#pragma unroll
    for (int i = 0; i < 8; i++) { e[i] = __expf(x[i] - m); s += e[i]; }
#pragma unroll
    for (int off = 32; off >= 1; off >>= 1) s += __shfl_xor(s, off, 64);
    if (lane == 0) ss[wave] = s;
    __syncthreads();
    s = ss[0] + ss[1] + ss[2] + ss[3];
    float inv = 1.0f / s;

    unsigned o[4];
#pragma unroll
    for (int i = 0; i < 4; i++) {
        unsigned lo = f2bf(e[2*i] * inv);
        unsigned hi = f2bf(e[2*i+1] * inv);
        o[i] = lo | (hi << 16);
    }
    ((uint4*)p)[tid] = make_uint4(o[0], o[1], o[2], o[3]);
}

// ---------- NT GEMM: C[m][n] = scale * sum_k A[m][k] * B[n][k]  (+bias) ----------
// 128x128 block tile, BK=32, 4 waves each 64x64 (2x2 wave grid), 16x16x32 bf16 MFMA.
// Fragment-major ("swizzled") LDS layout: tile rows grouped by 16; group g's
// chunk (row p in group, k-chunk q of 8 elems) lives at byte g*1024 + q*256 + p*16.
// Wave fragment read for group g is lane-linear: byte addr = g*1024 + lane*16 ->
// conflict-free ds_read_b128 by construction (R2 measured SQ_LDS_BANK_CONFLICT=0)
// and near-zero VALU address arithmetic. Staging inverts the mapping in the
// per-lane GLOBAL address (global_load_lds LDS dest is pinned to lane*16).
// 128x128 tile keeps acc at 64 AGPRs / 16 KB LDS -> ~2 blocks/CU so the
// vmcnt(0)+barrier drain overlaps with the other resident block (R2's 256-tile
// dropped occupancy and went latency-bound).
template<bool OUT_BF16, bool BIAS>
__global__ __launch_bounds__(256)
void gemm_nt(const unsigned short* __restrict__ A, const unsigned short* __restrict__ B,
             void* __restrict__ C, const float* __restrict__ bias,
             int lda, int ldb, int ldc, int nk, float scale,
             long long sA, long long sB, long long sC)
{
    __shared__ __align__(16) unsigned short As[128 * 32];   // 8 KB, groups 0..7
    __shared__ __align__(16) unsigned short Bs[128 * 32];   // 8 KB, groups 0..7

    const int tid  = threadIdx.x;
    const int lane = tid & 63;
    const int wave = tid >> 6;
    const int bz = blockIdx.z;
    A += (size_t)bz * sA;
    B += (size_t)bz * sB;
    const int bm = blockIdx.y * 128;
    const int bn = blockIdx.x * 128;

    // staging source mapping (inverse of fragment-major LDS layout):
    // call c, thread tid -> LDS byte c*4096 + tid*16
    //   group g = c*4 + (tid>>6), q = (tid>>4)&3, p = tid&15
    //   global row = c*64 + srow, col elems = scol
    const int srow = ((tid >> 6) << 4) + (tid & 15);
    const int scol = ((tid >> 4) & 3) * 8;
    const unsigned short* ga = A + (size_t)(bm + srow) * lda + scol;
    const unsigned short* gb = B + (size_t)(bn + srow) * ldb + scol;

    f32x4 acc[4][4];
#pragma unroll
    for (int i = 0; i < 4; i++)
#pragma unroll
        for (int j = 0; j < 4; j++) acc[i][j] = (f32x4){0.f, 0.f, 0.f, 0.f};

    const int wm = (wave & 1) * 64;       // wave m-offset
    const int wn = (wave >> 1) * 64;      // wave n-offset
    const int gA0 = (wave & 1) * 4;       // A fragment group base (4 groups/wave)
    const int gB0 = (wave >> 1) * 4;      // B fragment group base
    const int ln15 = lane & 15;
    const int quad = lane >> 4;

    for (int kt = 0; kt < nk; ++kt) {
        __syncthreads();
#pragma unroll
        for (int c = 0; c < 2; c++) {
            gld_lds16(ga + (size_t)c * 64 * lda, (unsigned short*)((char*)As + c*4096 + tid*16));
            gld_lds16(gb + (size_t)c * 64 * ldb, (unsigned short*)((char*)Bs + c*4096 + tid*16));
        }
        ga += 32; gb += 32;
        asm volatile("s_waitcnt vmcnt(0)" ::: "memory");
        __syncthreads();

        bf16x8 af[4], bfr[4];
#pragma unroll
        for (int i = 0; i < 4; i++)
            af[i] = *(const bf16x8*)&As[(gA0 + i) * 512 + lane * 8];
#pragma unroll
        for (int j = 0; j < 4; j++)
            bfr[j] = *(const bf16x8*)&Bs[(gB0 + j) * 512 + lane * 8];
#pragma unroll
        for (int i = 0; i < 4; i++)
#pragma unroll
            for (int j = 0; j < 4; j++)
                acc[i][j] = __builtin_amdgcn_mfma_f32_16x16x32_bf16(af[i], bfr[j], acc[i][j], 0, 0, 0);
    }

    // epilogue. C/D layout: col = lane&15, row = quad*4 + reg
    float bval[4];
    if (BIAS) {
#pragma unroll
        for (int j = 0; j < 4; j++) bval[j] = bias[bn + wn + j*16 + ln15];
    }
    unsigned short* Co16 = (unsigned short*)C + (size_t)bz * sC;
    float*          Co32 = (float*)C          + (size_t)bz * sC;
#pragma unroll
    for (int i = 0; i < 4; i++) {
        int r0 = bm + wm + i*16 + quad*4;
#pragma unroll
        for (int j = 0; j < 4; j++) {
            int c = bn + wn + j*16 + ln15;
#pragma unroll
            for (int r = 0; r < 4; r++) {
                float v = acc[i][j][r] * scale;
                if (OUT_BF16) Co16[(size_t)(r0 + r) * ldc + c] = f2bf(v);
                else          Co32[(size_t)(r0 + r) * ldc + c] = v + (BIAS ? bval[j] : 0.f);
            }
        }
    }
}

// ---------- launcher ----------
extern "C" void kernel_launch(void* const* d_in, const int* in_sizes, int n_in,
                              void* d_out, int out_size, void* d_ws, size_t ws_size,
                              hipStream_t stream) {
    const float* X  = (const float*)d_in[0];   // [4,2048,1024]
    const float* Wq = (const float*)d_in[1];   // [1024,1024]
    const float* Wk = (const float*)d_in[2];
    const float* Wv = (const float*)d_in[3];
    const float* Wo = (const float*)d_in[4];
    const float* bo = (const float*)d_in[5];   // [1024]
    float* out = (float*)d_out;

    size_t off = 0;
    auto alloc = [&](size_t bytes) {
        void* p = (char*)d_ws + off;
        off += (bytes + 255) & ~(size_t)255;
        return p;
    };
    unsigned short* Xbf  = (unsigned short*)alloc(8192ull * 1024 * 2);   // 16 MB (reused as AO)
    unsigned short* Wcat = (unsigned short*)alloc(3072ull * 1024 * 2);   //  6 MB  [n][k], q/k/v stacked
    unsigned short* WoT  = (unsigned short*)alloc(1024ull * 1024 * 2);   //  2 MB  [n][k]
    unsigned short* QKV  = (unsigned short*)alloc(8192ull * 3072 * 2);   // 48 MB  [8192][3072]
    unsigned short* VT   = (unsigned short*)alloc(4ull * 1024 * 2048 * 2); // 16 MB [b][n][m]
    unsigned short* Sc   = (unsigned short*)alloc(4ull * 2048 * 2048 * 2); // 32 MB scores/probs
    unsigned short* AO   = Xbf;  // X dead after G1

    // P0: X -> bf16
    cvt_kernel<<<(8192*1024/4 + 255)/256, 256, 0, stream>>>(X, Xbf, 8192*1024/4);
    // P1: weight transposes
    dim3 tb(32, 8);
    wtrans_kernel<<<dim3(32,32), tb, 0, stream>>>(Wq, Wcat);
    wtrans_kernel<<<dim3(32,32), tb, 0, stream>>>(Wk, Wcat + 1024*1024);
    wtrans_kernel<<<dim3(32,32), tb, 0, stream>>>(Wv, Wcat + 2*1024*1024);
    wtrans_kernel<<<dim3(32,32), tb, 0, stream>>>(Wo, WoT);

    // G1: QKV = Xbf @ Wcat^T   M=8192 N=3072 K=1024
    gemm_nt<true,false><<<dim3(3072/128, 8192/128, 1), 256, 0, stream>>>(
        Xbf, Wcat, QKV, nullptr, 1024, 1024, 3072, 1024/32, 1.0f, 0, 0, 0);

    // P2: V -> VT
    vtrans_kernel<<<dim3(64, 32, 4), tb, 0, stream>>>(QKV, VT);

    // G2: Sc = (Q @ K^T) / 32  per batch   M=N=2048 K=1024
    gemm_nt<true,false><<<dim3(2048/128, 2048/128, 4), 256, 0, stream>>>(
        QKV, QKV + 1024, Sc, nullptr, 3072, 3072, 2048, 1024/32, 0.03125f,
        2048ll*3072, 2048ll*3072, 2048ll*2048);

    // softmax in place
    softmax_kernel<<<8192, 256, 0, stream>>>(Sc);

    // G3: AO = P @ V  per batch   M=2048 N=1024 K=2048
    gemm_nt<true,false><<<dim3(1024/128, 2048/128, 4), 256, 0, stream>>>(
        Sc, VT, AO, nullptr, 2048, 2048, 1024, 2048/32, 1.0f,
        2048ll*2048, 1024ll*2048, 2048ll*1024);

    // G4: out = AO @ WoT^T + bo   M=8192 N=1024 K=1024, fp32 out
    gemm_nt<false,true><<<dim3(1024/128, 8192/128, 1), 256, 0, stream>>>(
        AO, WoT, out, bo, 1024, 1024, 1024, 1024/32, 1.0f, 0, 0, 0);

    (void)n_in; (void)in_sizes; (void)out_size; (void)ws_size;
}

// Round 4
// 345.967 us; speedup vs baseline: 1.1976x; 1.1976x over previous
//
#include <hip/hip_runtime.h>
#include <hip/hip_bf16.h>
#include <cstdint>

// ---------- types ----------
typedef __attribute__((ext_vector_type(8))) __bf16 bf16x8;
typedef __attribute__((ext_vector_type(4))) float  f32x4;

// float -> bf16 round-to-nearest-even
__device__ __forceinline__ unsigned short f2bf(float x) {
    union { float f; unsigned u; } v; v.f = x;
    unsigned r = v.u + 0x7fffu + ((v.u >> 16) & 1u);
    return (unsigned short)(r >> 16);
}

__device__ __forceinline__ void gld_lds16(const unsigned short* g, unsigned short* l) {
    __builtin_amdgcn_global_load_lds(
        (const __attribute__((address_space(1))) unsigned int*)g,
        (__attribute__((address_space(3))) unsigned int*)l,
        16, 0, 0);
}

// ---------- P0: fp32 -> bf16 convert ----------
__global__ void cvt_kernel(const float* __restrict__ in, unsigned short* __restrict__ out, int n4) {
    int i = blockIdx.x * blockDim.x + threadIdx.x;
    if (i < n4) {
        float4 f = ((const float4*)in)[i];
        ushort4 o;
        o.x = f2bf(f.x); o.y = f2bf(f.y); o.z = f2bf(f.z); o.w = f2bf(f.w);
        ((ushort4*)out)[i] = o;
    }
}

// ---------- P1: transpose-convert 1024x1024 fp32 W[k][n] -> bf16 out[n][k] ----------
__global__ void wtrans_kernel(const float* __restrict__ W, unsigned short* __restrict__ out) {
    __shared__ float tile[32][33];
    int bx = blockIdx.x;          // k tile
    int by = blockIdx.y;          // n tile
    int tx = threadIdx.x;         // 0..31
    int ty = threadIdx.y;         // 0..7
#pragma unroll
    for (int j = 0; j < 4; j++)
        tile[ty + j*8][tx] = W[(size_t)(bx*32 + ty + j*8) * 1024 + by*32 + tx];
    __syncthreads();
#pragma unroll
    for (int j = 0; j < 4; j++)
        out[(size_t)(by*32 + ty + j*8) * 1024 + bx*32 + tx] = f2bf(tile[tx][ty + j*8]);
}

// ---------- P2: transpose V (bf16): VT[b][n][m] = QKV[b*2048+m][2048+n] ----------
__global__ void vtrans_kernel(const unsigned short* __restrict__ qkv, unsigned short* __restrict__ vt) {
    __shared__ unsigned short tile[32][33];
    int b = blockIdx.z;
    const unsigned short* V = qkv + (size_t)b * 2048 * 3072 + 2048;
    unsigned short* out = vt + (size_t)b * 1024 * 2048;
    int bx = blockIdx.x;          // m tile (64 tiles)
    int by = blockIdx.y;          // n tile (32 tiles)
    int tx = threadIdx.x, ty = threadIdx.y;
#pragma unroll
    for (int j = 0; j < 4; j++)
        tile[ty + j*8][tx] = V[(size_t)(bx*32 + ty + j*8) * 3072 + by*32 + tx];
    __syncthreads();
#pragma unroll
    for (int j = 0; j < 4; j++)
        out[(size_t)(by*32 + ty + j*8) * 2048 + bx*32 + tx] = tile[tx][ty + j*8];
}

// ---------- softmax: one block per row of 2048 bf16, in place ----------
__global__ void softmax_kernel(unsigned short* __restrict__ S) {
    const size_t row = blockIdx.x;
    unsigned short* p = S + row * 2048;
    const int tid = threadIdx.x;
    const int wave = tid >> 6, lane = tid & 63;

    uint4 raw = ((const uint4*)p)[tid];   // 8 bf16 per thread
    unsigned u[4] = {raw.x, raw.y, raw.z, raw.w};
    float x[8];
#pragma unroll
    for (int i = 0; i < 4; i++) {
        x[2*i]   = __uint_as_float(u[i] << 16);
        x[2*i+1] = __uint_as_float(u[i] & 0xffff0000u);
    }
    float m = x[0];
#pragma unroll
    for (int i = 1; i < 8; i++) m = fmaxf(m, x[i]);
#pragma unroll
    for (int off = 32; off >= 1; off >>= 1) m = fmaxf(m, __shfl_xor(m, off, 64));
    __shared__ float sm[4], ss[4];
    if (lane == 0) sm[wave] = m;
    __syncthreads();
    m = fmaxf(fmaxf(sm[0], sm[1]), fmaxf(sm[2], sm[3]));

    float e[8], s = 0.f;
#pragma unroll
    for (int i = 0; i < 8; i++) { e[i] = __expf(x[i] - m); s += e[i]; }
#pragma unroll
    for (int off = 32; off >= 1; off >>= 1) s += __shfl_xor(s, off, 64);
    if (lane == 0) ss[wave] = s;
    __syncthreads();
    s = ss[0] + ss[1] + ss[2] + ss[3];
    float inv = 1.0f / s;

    unsigned o[4];
#pragma unroll
    for (int i = 0; i < 4; i++) {
        unsigned lo = f2bf(e[2*i] * inv);
        unsigned hi = f2bf(e[2*i+1] * inv);
        o[i] = lo | (hi << 16);
    }
    ((uint4*)p)[tid] = make_uint4(o[0], o[1], o[2], o[3]);
}

// ---------- NT GEMM: C[m][n] = scale * sum_k A[m][k] * B[n][k]  (+bias) ----------
// 128x128 block tile, BK=32, 4 waves each 64x64 (2x2 wave grid), 16x16x32 bf16 MFMA.
// XOR-swizzled LDS layout: row r (64 B = 4 chunks of 16 B) stores k-chunk q at
// unit r*4 + (q ^ ((r>>1)&3)).
//  - Staging keeps R1's contiguous lane order (lane l -> row l>>2); the chunk
//    permutation stays WITHIN the same 64 B row -> global coalescing identical
//    to R1 (R3 showed lane-scrambled staging costs ~30% on the VMEM pipe).
//  - Fragment read: byte = row*64 + (quad ^ ((ln15>>1)&3))*16 -> per-16-lane
//    phase exactly 2 lanes/bank-quad = free (m136). Kills R1's 6.3e6 conflicts.
template<bool OUT_BF16, bool BIAS>
__global__ __launch_bounds__(256)
void gemm_nt(const unsigned short* __restrict__ A, const unsigned short* __restrict__ B,
             void* __restrict__ C, const float* __restrict__ bias,
             int lda, int ldb, int ldc, int nk, float scale,
             long long sA, long long sB, long long sC)
{
    __shared__ __align__(16) unsigned short As[128 * 32];   // 8 KB
    __shared__ __align__(16) unsigned short Bs[128 * 32];   // 8 KB

    const int tid  = threadIdx.x;
    const int lane = tid & 63;
    const int wave = tid >> 6;
    const int bz = blockIdx.z;
    A += (size_t)bz * sA;
    B += (size_t)bz * sB;
    const int bm = blockIdx.y * 128;
    const int bn = blockIdx.x * 128;

    // staging: thread tid -> row tid>>2, chunk (tid&3)^((tid>>3)&3) (same 64 B row)
    const int srow = tid >> 2;
    const int scol = ((tid & 3) ^ ((tid >> 3) & 3)) * 8;
    const unsigned short* ga = A + (size_t)(bm + srow) * lda + scol;
    const unsigned short* gb = B + (size_t)(bn + srow) * ldb + scol;

    f32x4 acc[4][4];
#pragma unroll
    for (int i = 0; i < 4; i++)
#pragma unroll
        for (int j = 0; j < 4; j++) acc[i][j] = (f32x4){0.f, 0.f, 0.f, 0.f};

    const int wm = (wave & 1) * 64;       // wave m-offset
    const int wn = (wave >> 1) * 64;      // wave n-offset
    const int ln15 = lane & 15;
    const int quad = lane >> 4;
    // swizzled fragment k-offset (elements); uniform across the i-loop since
    // wm + i*16 contributes 0 to ((row>>1)&3)
    const int fko = (quad ^ ((ln15 >> 1) & 3)) * 8;

    for (int kt = 0; kt < nk; ++kt) {
        __syncthreads();
#pragma unroll
        for (int c = 0; c < 2; c++) {
            gld_lds16(ga + (size_t)c * 64 * lda, (unsigned short*)((char*)As + c*4096 + tid*16));
            gld_lds16(gb + (size_t)c * 64 * ldb, (unsigned short*)((char*)Bs + c*4096 + tid*16));
        }
        ga += 32; gb += 32;
        asm volatile("s_waitcnt vmcnt(0)" ::: "memory");
        __syncthreads();

        bf16x8 af[4], bfr[4];
#pragma unroll
        for (int i = 0; i < 4; i++)
            af[i] = *(const bf16x8*)&As[(wm + i*16 + ln15) * 32 + fko];
#pragma unroll
        for (int j = 0; j < 4; j++)
            bfr[j] = *(const bf16x8*)&Bs[(wn + j*16 + ln15) * 32 + fko];
#pragma unroll
        for (int i = 0; i < 4; i++)
#pragma unroll
            for (int j = 0; j < 4; j++)
                acc[i][j] = __builtin_amdgcn_mfma_f32_16x16x32_bf16(af[i], bfr[j], acc[i][j], 0, 0, 0);
    }

    // epilogue. C/D layout: col = lane&15, row = quad*4 + reg
    float bval[4];
    if (BIAS) {
#pragma unroll
        for (int j = 0; j < 4; j++) bval[j] = bias[bn + wn + j*16 + ln15];
    }
    unsigned short* Co16 = (unsigned short*)C + (size_t)bz * sC;
    float*          Co32 = (float*)C          + (size_t)bz * sC;
#pragma unroll
    for (int i = 0; i < 4; i++) {
        int r0 = bm + wm + i*16 + quad*4;
#pragma unroll
        for (int j = 0; j < 4; j++) {
            int c = bn + wn + j*16 + ln15;
#pragma unroll
            for (int r = 0; r < 4; r++) {
                float v = acc[i][j][r] * scale;
                if (OUT_BF16) Co16[(size_t)(r0 + r) * ldc + c] = f2bf(v);
                else          Co32[(size_t)(r0 + r) * ldc + c] = v + (BIAS ? bval[j] : 0.f);
            }
        }
    }
}

// ---------- launcher ----------
extern "C" void kernel_launch(void* const* d_in, const int* in_sizes, int n_in,
                              void* d_out, int out_size, void* d_ws, size_t ws_size,
                              hipStream_t stream) {
    const float* X  = (const float*)d_in[0];   // [4,2048,1024]
    const float* Wq = (const float*)d_in[1];   // [1024,1024]
    const float* Wk = (const float*)d_in[2];
    const float* Wv = (const float*)d_in[3];
    const float* Wo = (const float*)d_in[4];
    const float* bo = (const float*)d_in[5];   // [1024]
    float* out = (float*)d_out;

    size_t off = 0;
    auto alloc = [&](size_t bytes) {
        void* p = (char*)d_ws + off;
        off += (bytes + 255) & ~(size_t)255;
        return p;
    };
    unsigned short* Xbf  = (unsigned short*)alloc(8192ull * 1024 * 2);   // 16 MB (reused as AO)
    unsigned short* Wcat = (unsigned short*)alloc(3072ull * 1024 * 2);   //  6 MB  [n][k], q/k/v stacked
    unsigned short* WoT  = (unsigned short*)alloc(1024ull * 1024 * 2);   //  2 MB  [n][k]
    unsigned short* QKV  = (unsigned short*)alloc(8192ull * 3072 * 2);   // 48 MB  [8192][3072]
    unsigned short* VT   = (unsigned short*)alloc(4ull * 1024 * 2048 * 2); // 16 MB [b][n][m]
    unsigned short* Sc   = (unsigned short*)alloc(4ull * 2048 * 2048 * 2); // 32 MB scores/probs
    unsigned short* AO   = Xbf;  // X dead after G1

    // P0: X -> bf16
    cvt_kernel<<<(8192*1024/4 + 255)/256, 256, 0, stream>>>(X, Xbf, 8192*1024/4);
    // P1: weight transposes
    dim3 tb(32, 8);
    wtrans_kernel<<<dim3(32,32), tb, 0, stream>>>(Wq, Wcat);
    wtrans_kernel<<<dim3(32,32), tb, 0, stream>>>(Wk, Wcat + 1024*1024);
    wtrans_kernel<<<dim3(32,32), tb, 0, stream>>>(Wv, Wcat + 2*1024*1024);
    wtrans_kernel<<<dim3(32,32), tb, 0, stream>>>(Wo, WoT);

    // G1: QKV = Xbf @ Wcat^T   M=8192 N=3072 K=1024
    gemm_nt<true,false><<<dim3(3072/128, 8192/128, 1), 256, 0, stream>>>(
        Xbf, Wcat, QKV, nullptr, 1024, 1024, 3072, 1024/32, 1.0f, 0, 0, 0);

    // P2: V -> VT
    vtrans_kernel<<<dim3(64, 32, 4), tb, 0, stream>>>(QKV, VT);

    // G2: Sc = (Q @ K^T) / 32  per batch   M=N=2048 K=1024
    gemm_nt<true,false><<<dim3(2048/128, 2048/128, 4), 256, 0, stream>>>(
        QKV, QKV + 1024, Sc, nullptr, 3072, 3072, 2048, 1024/32, 0.03125f,
        2048ll*3072, 2048ll*3072, 2048ll*2048);

    // softmax in place
    softmax_kernel<<<8192, 256, 0, stream>>>(Sc);

    // G3: AO = P @ V  per batch   M=2048 N=1024 K=2048
    gemm_nt<true,false><<<dim3(1024/128, 2048/128, 4), 256, 0, stream>>>(
        Sc, VT, AO, nullptr, 2048, 2048, 1024, 2048/32, 1.0f,
        2048ll*2048, 1024ll*2048, 2048ll*1024);

    // G4: out = AO @ WoT^T + bo   M=8192 N=1024 K=1024, fp32 out
    gemm_nt<false,true><<<dim3(1024/128, 8192/128, 1), 256, 0, stream>>>(
        AO, WoT, out, bo, 1024, 1024, 1024, 1024/32, 1.0f, 0, 0, 0);

    (void)n_in; (void)in_sizes; (void)out_size; (void)ws_size;
}

// Round 5
// 309.362 us; speedup vs baseline: 1.3393x; 1.1183x over previous
//
#include <hip/hip_runtime.h>
#include <hip/hip_bf16.h>
#include <cstdint>

// ---------- types ----------
typedef __attribute__((ext_vector_type(8))) __bf16 bf16x8;
typedef __attribute__((ext_vector_type(4))) float  f32x4;

// float -> bf16 round-to-nearest-even
__device__ __forceinline__ unsigned short f2bf(float x) {
    union { float f; unsigned u; } v; v.f = x;
    unsigned r = v.u + 0x7fffu + ((v.u >> 16) & 1u);
    return (unsigned short)(r >> 16);
}
__device__ __forceinline__ unsigned pack2bf(float a, float b) {
    return (unsigned)f2bf(a) | ((unsigned)f2bf(b) << 16);
}

__device__ __forceinline__ void gld_lds16(const unsigned short* g, unsigned short* l) {
    __builtin_amdgcn_global_load_lds(
        (const __attribute__((address_space(1))) unsigned int*)g,
        (__attribute__((address_space(3))) unsigned int*)l,
        16, 0, 0);
}

// ---------- P0: fp32 -> bf16 convert ----------
__global__ void cvt_kernel(const float* __restrict__ in, unsigned short* __restrict__ out, int n4) {
    int i = blockIdx.x * blockDim.x + threadIdx.x;
    if (i < n4) {
        float4 f = ((const float4*)in)[i];
        ushort4 o;
        o.x = f2bf(f.x); o.y = f2bf(f.y); o.z = f2bf(f.z); o.w = f2bf(f.w);
        ((ushort4*)out)[i] = o;
    }
}

// ---------- P1: transpose-convert 1024x1024 fp32 W[k][n] -> bf16 out[n][k] ----------
__global__ void wtrans_kernel(const float* __restrict__ W, unsigned short* __restrict__ out) {
    __shared__ float tile[32][33];
    int bx = blockIdx.x, by = blockIdx.y;
    int tx = threadIdx.x, ty = threadIdx.y;
#pragma unroll
    for (int j = 0; j < 4; j++)
        tile[ty + j*8][tx] = W[(size_t)(bx*32 + ty + j*8) * 1024 + by*32 + tx];
    __syncthreads();
#pragma unroll
    for (int j = 0; j < 4; j++)
        out[(size_t)(by*32 + ty + j*8) * 1024 + bx*32 + tx] = f2bf(tile[tx][ty + j*8]);
}

// ---------- P2: transpose V (bf16): VT[b][n][m] = QKV[b*2048+m][2048+n] ----------
__global__ void vtrans_kernel(const unsigned short* __restrict__ qkv, unsigned short* __restrict__ vt) {
    __shared__ unsigned short tile[32][33];
    int b = blockIdx.z;
    const unsigned short* V = qkv + (size_t)b * 2048 * 3072 + 2048;
    unsigned short* out = vt + (size_t)b * 1024 * 2048;
    int bx = blockIdx.x, by = blockIdx.y;
    int tx = threadIdx.x, ty = threadIdx.y;
#pragma unroll
    for (int j = 0; j < 4; j++)
        tile[ty + j*8][tx] = V[(size_t)(bx*32 + ty + j*8) * 3072 + by*32 + tx];
    __syncthreads();
#pragma unroll
    for (int j = 0; j < 4; j++)
        out[(size_t)(by*32 + ty + j*8) * 2048 + bx*32 + tx] = tile[tx][ty + j*8];
}

// ---------- softmax: one block per row of 2048 bf16, in place ----------
__global__ void softmax_kernel(unsigned short* __restrict__ S) {
    const size_t row = blockIdx.x;
    unsigned short* p = S + row * 2048;
    const int tid = threadIdx.x;
    const int wave = tid >> 6, lane = tid & 63;

    uint4 raw = ((const uint4*)p)[tid];
    unsigned u[4] = {raw.x, raw.y, raw.z, raw.w};
    float x[8];
#pragma unroll
    for (int i = 0; i < 4; i++) {
        x[2*i]   = __uint_as_float(u[i] << 16);
        x[2*i+1] = __uint_as_float(u[i] & 0xffff0000u);
    }
    float m = x[0];
#pragma unroll
    for (int i = 1; i < 8; i++) m = fmaxf(m, x[i]);
#pragma unroll
    for (int off = 32; off >= 1; off >>= 1) m = fmaxf(m, __shfl_xor(m, off, 64));
    __shared__ float sm[4], ss[4];
    if (lane == 0) sm[wave] = m;
    __syncthreads();
    m = fmaxf(fmaxf(sm[0], sm[1]), fmaxf(sm[2], sm[3]));

    float e[8], s = 0.f;
#pragma unroll
    for (int i = 0; i < 8; i++) { e[i] = __expf(x[i] - m); s += e[i]; }
#pragma unroll
    for (int off = 32; off >= 1; off >>= 1) s += __shfl_xor(s, off, 64);
    if (lane == 0) ss[wave] = s;
    __syncthreads();
    s = ss[0] + ss[1] + ss[2] + ss[3];
    float inv = 1.0f / s;

    unsigned o[4];
#pragma unroll
    for (int i = 0; i < 4; i++)
        o[i] = pack2bf(e[2*i] * inv, e[2*i+1] * inv);
    ((uint4*)p)[tid] = make_uint4(o[0], o[1], o[2], o[3]);
}

// ---------- NT GEMM: C[m][n] = scale * sum_k A[m][k] * B[n][k]  (+bias) ----------
// 128x128 block tile, BK=64 (two 32-k sub-tiles per barrier), 4 waves each 64x64,
// 16x16x32 bf16 MFMA. XOR-swizzled LDS (R4: 0 conflicts, coalescing preserved).
// 8 loop-carried staging pointers (+=64/iter) avoid per-call 64-bit addr recompute.
// bf16 epilogue: per-wave LDS transpose (pitch 68 f32, 2-way banks = free) ->
// global_store_dwordx4, replacing 64 scattered 2-byte stores per thread.
template<bool OUT_BF16, bool BIAS>
__global__ __launch_bounds__(256)
void gemm_nt(const unsigned short* __restrict__ A, const unsigned short* __restrict__ B,
             void* __restrict__ C, const float* __restrict__ bias,
             int lda, int ldb, int ldc, int nk2, float scale,
             long long sA, long long sB, long long sC)
{
    // 32 KB: A sub-tiles t=0,1 at 0/8 KB; B sub-tiles at 16/24 KB. Each sub-tile
    // 128 rows x 32 k-elems, row = 64 B of 4 xor-swizzled 16 B chunks.
    __shared__ __align__(16) char smem[32768];
    unsigned short* As = (unsigned short*)smem;            // [2][4096]
    unsigned short* Bs = (unsigned short*)(smem + 16384);  // [2][4096]

    const int tid  = threadIdx.x;
    const int lane = tid & 63;
    const int wave = tid >> 6;
    const int bz = blockIdx.z;
    A += (size_t)bz * sA;
    B += (size_t)bz * sB;
    const int bm = blockIdx.y * 128;
    const int bn = blockIdx.x * 128;

    // staging: thread tid -> row tid>>2, chunk (tid&3)^((tid>>3)&3) within 64 B row
    const int srow = tid >> 2;
    const int scol = ((tid & 3) ^ ((tid >> 3) & 3)) * 8;

    // 8 loop-carried pointers: [matrix][c][t], c = row-half, t = k sub-tile
    const unsigned short* pa0 = A + (size_t)(bm + srow) * lda + scol;          // c0 t0
    const unsigned short* pa1 = pa0 + 32;                                      // c0 t1
    const unsigned short* pa2 = A + (size_t)(bm + 64 + srow) * lda + scol;     // c1 t0
    const unsigned short* pa3 = pa2 + 32;                                      // c1 t1
    const unsigned short* pb0 = B + (size_t)(bn + srow) * ldb + scol;
    const unsigned short* pb1 = pb0 + 32;
    const unsigned short* pb2 = B + (size_t)(bn + 64 + srow) * ldb + scol;
    const unsigned short* pb3 = pb2 + 32;

    f32x4 acc[4][4];
#pragma unroll
    for (int i = 0; i < 4; i++)
#pragma unroll
        for (int j = 0; j < 4; j++) acc[i][j] = (f32x4){0.f, 0.f, 0.f, 0.f};

    const int wm = (wave & 1) * 64;
    const int wn = (wave >> 1) * 64;
    const int ln15 = lane & 15;
    const int quad = lane >> 4;
    const int fko = (quad ^ ((ln15 >> 1) & 3)) * 8;   // swizzled frag k-offset (elems)

    const int ldsoff = tid * 16;   // byte offset of this thread's 16 B slot

    for (int kt = 0; kt < nk2; ++kt) {
        __syncthreads();
        gld_lds16(pa0, (unsigned short*)(smem         + ldsoff));          // A t0 c0
        gld_lds16(pa2, (unsigned short*)(smem + 4096  + ldsoff));          // A t0 c1
        gld_lds16(pa1, (unsigned short*)(smem + 8192  + ldsoff));          // A t1 c0
        gld_lds16(pa3, (unsigned short*)(smem + 12288 + ldsoff));          // A t1 c1
        gld_lds16(pb0, (unsigned short*)(smem + 16384 + ldsoff));
        gld_lds16(pb2, (unsigned short*)(smem + 20480 + ldsoff));
        gld_lds16(pb1, (unsigned short*)(smem + 24576 + ldsoff));
        gld_lds16(pb3, (unsigned short*)(smem + 28672 + ldsoff));
        pa0 += 64; pa1 += 64; pa2 += 64; pa3 += 64;
        pb0 += 64; pb1 += 64; pb2 += 64; pb3 += 64;
        asm volatile("s_waitcnt vmcnt(0)" ::: "memory");
        __syncthreads();

#pragma unroll
        for (int t = 0; t < 2; t++) {
            bf16x8 af[4], bfr[4];
#pragma unroll
            for (int i = 0; i < 4; i++)
                af[i] = *(const bf16x8*)&As[t*4096 + (wm + i*16 + ln15) * 32 + fko];
#pragma unroll
            for (int j = 0; j < 4; j++)
                bfr[j] = *(const bf16x8*)&Bs[t*4096 + (wn + j*16 + ln15) * 32 + fko];
#pragma unroll
            for (int i = 0; i < 4; i++)
#pragma unroll
                for (int j = 0; j < 4; j++)
                    acc[i][j] = __builtin_amdgcn_mfma_f32_16x16x32_bf16(af[i], bfr[j], acc[i][j], 0, 0, 0);
        }
    }

    // ---------------- epilogue ----------------
    // C/D layout: col = ln15, row = quad*4 + reg
    if (OUT_BF16) {
        __syncthreads();   // all waves done reading K-loop LDS before reuse
        // per-wave fp32 scratch: 16 rows x 64 cols, pitch 68 (272 B, 16 B aligned)
        float* ep = (float*)(smem + wave * 4352);
        unsigned short* Co = (unsigned short*)C + (size_t)bz * sC;
#pragma unroll
        for (int i = 0; i < 4; i++) {
            // write: local row = quad*4+r, local col = j*16+ln15
#pragma unroll
            for (int j = 0; j < 4; j++) {
#pragma unroll
                for (int r = 0; r < 4; r++)
                    ep[(quad*4 + r) * 68 + j*16 + ln15] = acc[i][j][r] * scale;
            }
            // read back 8 consecutive f32/lane, two passes of 8 rows
            __builtin_amdgcn_s_waitcnt(0);  // lgkmcnt(0): within-wave LDS RAW
#pragma unroll
            for (int p = 0; p < 2; p++) {
                int lrow = p*8 + (lane >> 3);
                int col0 = (lane & 7) * 8;
                float4 lo = *(const float4*)&ep[lrow * 68 + col0];
                float4 hi = *(const float4*)&ep[lrow * 68 + col0 + 4];
                uint4 o;
                o.x = pack2bf(lo.x, lo.y);
                o.y = pack2bf(lo.z, lo.w);
                o.z = pack2bf(hi.x, hi.y);
                o.w = pack2bf(hi.z, hi.w);
                *(uint4*)&Co[(size_t)(bm + wm + i*16 + lrow) * ldc + bn + wn + col0] = o;
            }
            // next i reuses ep; reads above must complete before overwrite —
            // same wave, compiler inserts lgkmcnt as needed.
            __builtin_amdgcn_s_waitcnt(0);
        }
    } else {
        float bval[4];
        if (BIAS) {
#pragma unroll
            for (int j = 0; j < 4; j++) bval[j] = bias[bn + wn + j*16 + ln15];
        }
        float* Co = (float*)C + (size_t)bz * sC;
#pragma unroll
        for (int i = 0; i < 4; i++) {
            int r0 = bm + wm + i*16 + quad*4;
#pragma unroll
            for (int j = 0; j < 4; j++) {
                int c = bn + wn + j*16 + ln15;
#pragma unroll
                for (int r = 0; r < 4; r++) {
                    float v = acc[i][j][r] * scale;
                    Co[(size_t)(r0 + r) * ldc + c] = v + (BIAS ? bval[j] : 0.f);
                }
            }
        }
    }
}

// ---------- launcher ----------
extern "C" void kernel_launch(void* const* d_in, const int* in_sizes, int n_in,
                              void* d_out, int out_size, void* d_ws, size_t ws_size,
                              hipStream_t stream) {
    const float* X  = (const float*)d_in[0];   // [4,2048,1024]
    const float* Wq = (const float*)d_in[1];   // [1024,1024]
    const float* Wk = (const float*)d_in[2];
    const float* Wv = (const float*)d_in[3];
    const float* Wo = (const float*)d_in[4];
    const float* bo = (const float*)d_in[5];   // [1024]
    float* out = (float*)d_out;

    size_t off = 0;
    auto alloc = [&](size_t bytes) {
        void* p = (char*)d_ws + off;
        off += (bytes + 255) & ~(size_t)255;
        return p;
    };
    unsigned short* Xbf  = (unsigned short*)alloc(8192ull * 1024 * 2);     // 16 MB (reused as AO)
    unsigned short* Wcat = (unsigned short*)alloc(3072ull * 1024 * 2);     //  6 MB
    unsigned short* WoT  = (unsigned short*)alloc(1024ull * 1024 * 2);     //  2 MB
    unsigned short* QKV  = (unsigned short*)alloc(8192ull * 3072 * 2);     // 48 MB
    unsigned short* VT   = (unsigned short*)alloc(4ull * 1024 * 2048 * 2); // 16 MB
    unsigned short* Sc   = (unsigned short*)alloc(4ull * 2048 * 2048 * 2); // 32 MB
    unsigned short* AO   = Xbf;

    cvt_kernel<<<(8192*1024/4 + 255)/256, 256, 0, stream>>>(X, Xbf, 8192*1024/4);
    dim3 tb(32, 8);
    wtrans_kernel<<<dim3(32,32), tb, 0, stream>>>(Wq, Wcat);
    wtrans_kernel<<<dim3(32,32), tb, 0, stream>>>(Wk, Wcat + 1024*1024);
    wtrans_kernel<<<dim3(32,32), tb, 0, stream>>>(Wv, Wcat + 2*1024*1024);
    wtrans_kernel<<<dim3(32,32), tb, 0, stream>>>(Wo, WoT);

    // G1: QKV = Xbf @ Wcat^T   M=8192 N=3072 K=1024 (nk2 = 1024/64 = 16)
    gemm_nt<true,false><<<dim3(3072/128, 8192/128, 1), 256, 0, stream>>>(
        Xbf, Wcat, QKV, nullptr, 1024, 1024, 3072, 16, 1.0f, 0, 0, 0);

    vtrans_kernel<<<dim3(64, 32, 4), tb, 0, stream>>>(QKV, VT);

    // G2: Sc = (Q @ K^T) / 32  per batch   M=N=2048 K=1024
    gemm_nt<true,false><<<dim3(2048/128, 2048/128, 4), 256, 0, stream>>>(
        QKV, QKV + 1024, Sc, nullptr, 3072, 3072, 2048, 16, 0.03125f,
        2048ll*3072, 2048ll*3072, 2048ll*2048);

    softmax_kernel<<<8192, 256, 0, stream>>>(Sc);

    // G3: AO = P @ V  per batch   M=2048 N=1024 K=2048 (nk2 = 32)
    gemm_nt<true,false><<<dim3(1024/128, 2048/128, 4), 256, 0, stream>>>(
        Sc, VT, AO, nullptr, 2048, 2048, 1024, 32, 1.0f,
        2048ll*2048, 1024ll*2048, 2048ll*1024);

    // G4: out = AO @ WoT^T + bo   M=8192 N=1024 K=1024, fp32 out
    gemm_nt<false,true><<<dim3(1024/128, 8192/128, 1), 256, 0, stream>>>(
        AO, WoT, out, bo, 1024, 1024, 1024, 16, 1.0f, 0, 0, 0);

    (void)n_in; (void)in_sizes; (void)out_size; (void)ws_size;
}

// Round 6
// 308.462 us; speedup vs baseline: 1.3432x; 1.0029x over previous
//
#include <hip/hip_runtime.h>
#include <hip/hip_bf16.h>
#include <cstdint>

// ---------- types ----------
typedef __attribute__((ext_vector_type(8))) __bf16 bf16x8;
typedef __attribute__((ext_vector_type(4))) float  f32x4;

// float -> bf16 round-to-nearest-even
__device__ __forceinline__ unsigned short f2bf(float x) {
    union { float f; unsigned u; } v; v.f = x;
    unsigned r = v.u + 0x7fffu + ((v.u >> 16) & 1u);
    return (unsigned short)(r >> 16);
}
__device__ __forceinline__ unsigned pack2bf(float a, float b) {
    return (unsigned)f2bf(a) | ((unsigned)f2bf(b) << 16);
}

__device__ __forceinline__ void gld_lds16(const unsigned short* g, unsigned short* l) {
    __builtin_amdgcn_global_load_lds(
        (const __attribute__((address_space(1))) unsigned int*)g,
        (__attribute__((address_space(3))) unsigned int*)l,
        16, 0, 0);
}

// ---------- P0: fp32 -> bf16 convert ----------
__global__ void cvt_kernel(const float* __restrict__ in, unsigned short* __restrict__ out, int n4) {
    int i = blockIdx.x * blockDim.x + threadIdx.x;
    if (i < n4) {
        float4 f = ((const float4*)in)[i];
        ushort4 o;
        o.x = f2bf(f.x); o.y = f2bf(f.y); o.z = f2bf(f.z); o.w = f2bf(f.w);
        ((ushort4*)out)[i] = o;
    }
}

// ---------- P1: pack fp32 W[k][n] (1024x1024) into MFMA-B-fragment chunks ----------
// chunk (nt, k32) = 64 lanes x 16 B; lane l = q*16+r holds bf16 of
// W[k32*32 + q*8 + e][nt*16 + r], e = 0..7. out chunk index = nt*32 + k32.
__global__ void wpack_kernel(const float* __restrict__ W, unsigned short* __restrict__ out) {
    int tid  = threadIdx.x;
    int lane = tid & 63;
    int chunk = blockIdx.x * 4 + (tid >> 6);        // 2048 chunks
    int nt = chunk >> 5, k32 = chunk & 31;
    int r = lane & 15, q = lane >> 4;
    const float* src = W + (size_t)(k32*32 + q*8) * 1024 + nt*16 + r;
    unsigned o[4];
#pragma unroll
    for (int i = 0; i < 4; i++)
        o[i] = pack2bf(src[(size_t)(2*i) * 1024], src[(size_t)(2*i+1) * 1024]);
    *(uint4*)(out + (size_t)chunk * 512 + lane * 8) = make_uint4(o[0], o[1], o[2], o[3]);
}

// ---------- softmax: one block per row of 2048 bf16, in place ----------
__global__ void softmax_kernel(unsigned short* __restrict__ S) {
    const size_t row = blockIdx.x;
    unsigned short* p = S + row * 2048;
    const int tid = threadIdx.x;
    const int wave = tid >> 6, lane = tid & 63;

    uint4 raw = ((const uint4*)p)[tid];
    unsigned u[4] = {raw.x, raw.y, raw.z, raw.w};
    float x[8];
#pragma unroll
    for (int i = 0; i < 4; i++) {
        x[2*i]   = __uint_as_float(u[i] << 16);
        x[2*i+1] = __uint_as_float(u[i] & 0xffff0000u);
    }
    float m = x[0];
#pragma unroll
    for (int i = 1; i < 8; i++) m = fmaxf(m, x[i]);
#pragma unroll
    for (int off = 32; off >= 1; off >>= 1) m = fmaxf(m, __shfl_xor(m, off, 64));
    __shared__ float sm[4], ss[4];
    if (lane == 0) sm[wave] = m;
    __syncthreads();
    m = fmaxf(fmaxf(sm[0], sm[1]), fmaxf(sm[2], sm[3]));

    float e[8], s = 0.f;
#pragma unroll
    for (int i = 0; i < 8; i++) { e[i] = __expf(x[i] - m); s += e[i]; }
#pragma unroll
    for (int off = 32; off >= 1; off >>= 1) s += __shfl_xor(s, off, 64);
    if (lane == 0) ss[wave] = s;
    __syncthreads();
    s = ss[0] + ss[1] + ss[2] + ss[3];
    float inv = 1.0f / s;

    unsigned o[4];
#pragma unroll
    for (int i = 0; i < 4; i++)
        o[i] = pack2bf(e[2*i] * inv, e[2*i+1] * inv);
    ((uint4*)p)[tid] = make_uint4(o[0], o[1], o[2], o[3]);
}

// ---------- NT GEMM with packed-B: C[m][n] = scale * sum_k A[m][k] * Bpk(n,k) ----------
// 128x128 block tile, BK=64, 4 waves 64x64 each, 16x16x32 bf16 MFMA.
// A: row-major through LDS (xor-swizzled, conflict-free, coalesced staging).
// B: fragment-packed global chunks -> one coalesced global_load_dwordx4 per frag,
//    no LDS at all (halves LDS pipe traffic; R5 analysis: LDS pipe 575 cyc vs
//    MFMA 310 cyc per block-k32 -> now ~255 vs 310, MFMA-bound).
// EPI: 0 = f32+bias direct; 1 = bf16 row-major (LDS-transpose, coalesced dwordx4);
//      2 = QKV triple: Q row-major bf16 / K fragment-packed / V packed-transposed.
template<int EPI>
__global__ __launch_bounds__(256)
void gemm_pk(const unsigned short* __restrict__ A, const unsigned short* __restrict__ Bpk,
             void* __restrict__ C, unsigned short* __restrict__ Ck, unsigned short* __restrict__ Cv,
             const float* __restrict__ bias,
             int lda, int ldc, int KS, int nk2, float scale,
             long long sA, long long sB, long long sC)
{
    constexpr int SMEM = (EPI == 2) ? 34816 : ((EPI == 1) ? 17408 : 16384);
    __shared__ __align__(16) char smem[SMEM];
    unsigned short* As = (unsigned short*)smem;    // [2][128][32] = 16 KB

    const int tid  = threadIdx.x;
    const int lane = tid & 63;
    const int wave = tid >> 6;
    const int bz = blockIdx.z;
    A   += (size_t)bz * sA;
    Bpk += (size_t)bz * sB;
    const int bm = blockIdx.y * 128;
    const int bn = blockIdx.x * 128;

    // A staging: thread tid -> row tid>>2, chunk (tid&3)^((tid>>3)&3) within 64 B row
    const int srow = tid >> 2;
    const int scol = ((tid & 3) ^ ((tid >> 3) & 3)) * 8;
    const unsigned short* pa0 = A + (size_t)(bm + srow) * lda + scol;       // rows 0-63,  t0
    const unsigned short* pa1 = pa0 + 32;                                   // rows 0-63,  t1
    const unsigned short* pa2 = A + (size_t)(bm + 64 + srow) * lda + scol;  // rows 64-127,t0
    const unsigned short* pa3 = pa2 + 32;                                   // rows 64-127,t1

    const int wm = (wave & 1) * 64;
    const int wn = (wave >> 1) * 64;
    const int ln15 = lane & 15;
    const int quad = lane >> 4;
    const int fko = (quad ^ ((ln15 >> 1) & 3)) * 8;   // swizzled A-frag k-offset

    // B chunk pointers, one per j-fragment (advance 2 chunks = 1024 ushorts / iter)
    const unsigned short* pb[4];
#pragma unroll
    for (int j = 0; j < 4; j++)
        pb[j] = Bpk + (size_t)(((bn + wn + j*16) >> 4) * KS) * 512 + lane * 8;

    f32x4 acc[4][4];
#pragma unroll
    for (int i = 0; i < 4; i++)
#pragma unroll
        for (int j = 0; j < 4; j++) acc[i][j] = (f32x4){0.f, 0.f, 0.f, 0.f};

    const int ldsoff = tid * 16;

    for (int kt = 0; kt < nk2; ++kt) {
        __syncthreads();
        gld_lds16(pa0, (unsigned short*)(smem + ldsoff));           // t0 rows 0-63
        gld_lds16(pa2, (unsigned short*)(smem + 4096  + ldsoff));   // t0 rows 64-127
        gld_lds16(pa1, (unsigned short*)(smem + 8192  + ldsoff));   // t1 rows 0-63
        gld_lds16(pa3, (unsigned short*)(smem + 12288 + ldsoff));   // t1 rows 64-127
        pa0 += 64; pa1 += 64; pa2 += 64; pa3 += 64;
        bf16x8 b0[4], b1[4];
#pragma unroll
        for (int j = 0; j < 4; j++) {
            b0[j] = *(const bf16x8*)(pb[j]);
            b1[j] = *(const bf16x8*)(pb[j] + 512);
            pb[j] += 1024;
        }
        asm volatile("s_waitcnt vmcnt(0)" ::: "memory");
        __syncthreads();

#pragma unroll
        for (int t = 0; t < 2; t++) {
            bf16x8 af[4];
#pragma unroll
            for (int i = 0; i < 4; i++)
                af[i] = *(const bf16x8*)&As[t*4096 + (wm + i*16 + ln15) * 32 + fko];
#pragma unroll
            for (int i = 0; i < 4; i++)
#pragma unroll
                for (int j = 0; j < 4; j++)
                    acc[i][j] = __builtin_amdgcn_mfma_f32_16x16x32_bf16(
                        af[i], t ? b1[j] : b0[j], acc[i][j], 0, 0, 0);
        }
    }

    // ---------------- epilogue ----------------
    // C/D layout: col = ln15, row = quad*4 + reg
    if (EPI == 0) {
        float bval[4];
#pragma unroll
        for (int j = 0; j < 4; j++) bval[j] = bias[bn + wn + j*16 + ln15];
        float* Co = (float*)C + (size_t)bz * sC;
#pragma unroll
        for (int i = 0; i < 4; i++) {
            int r0 = bm + wm + i*16 + quad*4;
#pragma unroll
            for (int j = 0; j < 4; j++) {
                int c = bn + wn + j*16 + ln15;
#pragma unroll
                for (int r = 0; r < 4; r++)
                    Co[(size_t)(r0 + r) * ldc + c] = acc[i][j][r] * scale + bval[j];
            }
        }
    } else if (EPI == 1) {
        __syncthreads();
        float* ep = (float*)(smem + wave * 4352);   // 16 x 68 f32
        unsigned short* Co = (unsigned short*)C + (size_t)bz * sC;
#pragma unroll
        for (int i = 0; i < 4; i++) {
#pragma unroll
            for (int j = 0; j < 4; j++)
#pragma unroll
                for (int r = 0; r < 4; r++)
                    ep[(quad*4 + r) * 68 + j*16 + ln15] = acc[i][j][r] * scale;
            __builtin_amdgcn_s_waitcnt(0);
#pragma unroll
            for (int p = 0; p < 2; p++) {
                int lrow = p*8 + (lane >> 3);
                int col0 = (lane & 7) * 8;
                float4 lo = *(const float4*)&ep[lrow * 68 + col0];
                float4 hi = *(const float4*)&ep[lrow * 68 + col0 + 4];
                uint4 o;
                o.x = pack2bf(lo.x, lo.y); o.y = pack2bf(lo.z, lo.w);
                o.z = pack2bf(hi.x, hi.y); o.w = pack2bf(hi.z, hi.w);
                *(uint4*)&Co[(size_t)(bm + wm + i*16 + lrow) * ldc + bn + wn + col0] = o;
            }
            __builtin_amdgcn_s_waitcnt(0);
        }
    } else {  // EPI == 2: Q row-major / K packed / V packed-transposed
        __syncthreads();
        float* ep = (float*)(smem + wave * 8704);   // 32 x 68 f32
        const int region = bn >> 10;                // 0=Q, 1=K, 2=V (block-uniform)
#pragma unroll
        for (int half = 0; half < 2; half++) {
#pragma unroll
            for (int ii = 0; ii < 2; ii++) {
                int i = half*2 + ii;
#pragma unroll
                for (int j = 0; j < 4; j++)
#pragma unroll
                    for (int r = 0; r < 4; r++)
                        ep[(ii*16 + quad*4 + r) * 68 + j*16 + ln15] = acc[i][j][r] * scale;
            }
            __builtin_amdgcn_s_waitcnt(0);
            const int mrow0 = bm + wm + half*32;    // global m of scratch row 0 (32-aligned)
            if (region == 0) {
                unsigned short* Q = (unsigned short*)C;
#pragma unroll
                for (int p = 0; p < 4; p++) {
                    int lrow = p*8 + (lane >> 3);
                    int col0 = (lane & 7) * 8;
                    float4 lo = *(const float4*)&ep[lrow * 68 + col0];
                    float4 hi = *(const float4*)&ep[lrow * 68 + col0 + 4];
                    uint4 o;
                    o.x = pack2bf(lo.x, lo.y); o.y = pack2bf(lo.z, lo.w);
                    o.z = pack2bf(hi.x, hi.y); o.w = pack2bf(hi.z, hi.w);
                    *(uint4*)&Q[(size_t)(mrow0 + lrow) * ldc + bn + wn + col0] = o;
                }
            } else if (region == 1) {
                // K chunk (m_tile, d32): lane(q,r) = K[mt*16+r][d32*32+q*8+e]
#pragma unroll
                for (int mt = 0; mt < 2; mt++)
#pragma unroll
                    for (int c = 0; c < 2; c++) {
                        float4 f0 = *(const float4*)&ep[(mt*16 + ln15) * 68 + c*32 + quad*8];
                        float4 f1 = *(const float4*)&ep[(mt*16 + ln15) * 68 + c*32 + quad*8 + 4];
                        uint4 o;
                        o.x = pack2bf(f0.x, f0.y); o.y = pack2bf(f0.z, f0.w);
                        o.z = pack2bf(f1.x, f1.y); o.w = pack2bf(f1.z, f1.w);
                        int cid = ((mrow0 + mt*16) >> 4) * 32 + ((bn - 1024 + wn + c*32) >> 5);
                        *(uint4*)(Ck + (size_t)cid * 512 + lane * 8) = o;
                    }
            } else {
                // V chunk (d_tile, s32): lane(q,r) = V[s32*32+q*8+e][dt*16+r] (transpose)
                int s32 = mrow0 >> 5;
#pragma unroll
                for (int dt = 0; dt < 4; dt++) {
                    float v[8];
#pragma unroll
                    for (int e = 0; e < 8; e++)
                        v[e] = ep[(quad*8 + e) * 68 + dt*16 + ln15];
                    uint4 o;
                    o.x = pack2bf(v[0], v[1]); o.y = pack2bf(v[2], v[3]);
                    o.z = pack2bf(v[4], v[5]); o.w = pack2bf(v[6], v[7]);
                    int cid = (((bn - 2048 + wn) >> 4) + dt) * 256 + s32;
                    *(uint4*)(Cv + (size_t)cid * 512 + lane * 8) = o;
                }
            }
            __builtin_amdgcn_s_waitcnt(0);
        }
    }
}

// ---------- launcher ----------
extern "C" void kernel_launch(void* const* d_in, const int* in_sizes, int n_in,
                              void* d_out, int out_size, void* d_ws, size_t ws_size,
                              hipStream_t stream) {
    const float* X  = (const float*)d_in[0];   // [4,2048,1024]
    const float* Wq = (const float*)d_in[1];   // [1024,1024]
    const float* Wk = (const float*)d_in[2];
    const float* Wv = (const float*)d_in[3];
    const float* Wo = (const float*)d_in[4];
    const float* bo = (const float*)d_in[5];   // [1024]
    float* out = (float*)d_out;

    size_t off = 0;
    auto alloc = [&](size_t bytes) {
        void* p = (char*)d_ws + off;
        off += (bytes + 255) & ~(size_t)255;
        return p;
    };
    unsigned short* Xbf  = (unsigned short*)alloc(8192ull * 1024 * 2);      // 16 MB (reused as AO)
    unsigned short* Wpk  = (unsigned short*)alloc(192ull * 32 * 512 * 2);   //  6 MB packed Wq|Wk|Wv
    unsigned short* Wopk = (unsigned short*)alloc(64ull * 32 * 512 * 2);    //  2 MB packed Wo
    unsigned short* Qrm  = (unsigned short*)alloc(8192ull * 1024 * 2);      // 16 MB row-major Q
    unsigned short* Kpk  = (unsigned short*)alloc(512ull * 32 * 512 * 2);   // 16 MB packed K
    unsigned short* Vpk  = (unsigned short*)alloc(64ull * 256 * 512 * 2);   // 16 MB packed V^T
    unsigned short* Sc   = (unsigned short*)alloc(4ull * 2048 * 2048 * 2);  // 32 MB scores/probs
    unsigned short* AO   = Xbf;   // X dead after G1

    cvt_kernel<<<(8192*1024/4 + 255)/256, 256, 0, stream>>>(X, Xbf, 8192*1024/4);
    wpack_kernel<<<512, 256, 0, stream>>>(Wq, Wpk);
    wpack_kernel<<<512, 256, 0, stream>>>(Wk, Wpk + 64*32*512);
    wpack_kernel<<<512, 256, 0, stream>>>(Wv, Wpk + 128*32*512);
    wpack_kernel<<<512, 256, 0, stream>>>(Wo, Wopk);

    // G1: [Q|K|V] = Xbf @ W^T   M=8192 N=3072 K=1024; Q row-major, K/V packed
    gemm_pk<2><<<dim3(3072/128, 8192/128, 1), 256, 0, stream>>>(
        Xbf, Wpk, Qrm, Kpk, Vpk, nullptr, 1024, 1024, 32, 16, 1.0f, 0, 0, 0);

    // G2: Sc = (Q @ K^T)/32 per batch   M=N=2048 K=1024
    gemm_pk<1><<<dim3(2048/128, 2048/128, 4), 256, 0, stream>>>(
        Qrm, Kpk, Sc, nullptr, nullptr, nullptr, 1024, 2048, 32, 16, 0.03125f,
        2048ll*1024, 128ll*32*512, 2048ll*2048);

    softmax_kernel<<<8192, 256, 0, stream>>>(Sc);

    // G3: AO = P @ V per batch   M=2048 N=1024 K=2048
    gemm_pk<1><<<dim3(1024/128, 2048/128, 4), 256, 0, stream>>>(
        Sc, Vpk, AO, nullptr, nullptr, nullptr, 2048, 1024, 256, 32, 1.0f,
        2048ll*2048, 64ll*512, 2048ll*1024);

    // G4: out = AO @ WoT^T + bo   M=8192 N=1024 K=1024, fp32 out
    gemm_pk<0><<<dim3(1024/128, 8192/128, 1), 256, 0, stream>>>(
        AO, Wopk, out, nullptr, nullptr, bo, 1024, 1024, 32, 16, 1.0f, 0, 0, 0);

    (void)n_in; (void)in_sizes; (void)out_size; (void)ws_size;
}

// Round 7
// 306.052 us; speedup vs baseline: 1.3538x; 1.0079x over previous
//
#include <hip/hip_runtime.h>
#include <hip/hip_bf16.h>
#include <cstdint>

// ---------- types ----------
typedef __attribute__((ext_vector_type(8))) __bf16 bf16x8;
typedef __attribute__((ext_vector_type(4))) float  f32x4;

// float -> bf16 round-to-nearest-even
__device__ __forceinline__ unsigned short f2bf(float x) {
    union { float f; unsigned u; } v; v.f = x;
    unsigned r = v.u + 0x7fffu + ((v.u >> 16) & 1u);
    return (unsigned short)(r >> 16);
}
__device__ __forceinline__ unsigned pack2bf(float a, float b) {
    return (unsigned)f2bf(a) | ((unsigned)f2bf(b) << 16);
}

__device__ __forceinline__ void gld_lds16(const unsigned short* g, unsigned short* l) {
    __builtin_amdgcn_global_load_lds(
        (const __attribute__((address_space(1))) unsigned int*)g,
        (__attribute__((address_space(3))) unsigned int*)l,
        16, 0, 0);
}

// ---------- P0: fp32 -> bf16 convert ----------
__global__ void cvt_kernel(const float* __restrict__ in, unsigned short* __restrict__ out, int n4) {
    int i = blockIdx.x * blockDim.x + threadIdx.x;
    if (i < n4) {
        float4 f = ((const float4*)in)[i];
        ushort4 o;
        o.x = f2bf(f.x); o.y = f2bf(f.y); o.z = f2bf(f.z); o.w = f2bf(f.w);
        ((ushort4*)out)[i] = o;
    }
}

// ---------- P1: pack fp32 W[k][n] (1024x1024) into MFMA-B-fragment chunks ----------
// chunk (nt, k32) = 64 lanes x 16 B; lane l = q*16+r holds bf16 of
// W[k32*32 + q*8 + e][nt*16 + r], e = 0..7. out chunk index = nt*32 + k32.
__global__ void wpack_kernel(const float* __restrict__ W, unsigned short* __restrict__ out) {
    int tid  = threadIdx.x;
    int lane = tid & 63;
    int chunk = blockIdx.x * 4 + (tid >> 6);        // 2048 chunks
    int nt = chunk >> 5, k32 = chunk & 31;
    int r = lane & 15, q = lane >> 4;
    const float* src = W + (size_t)(k32*32 + q*8) * 1024 + nt*16 + r;
    unsigned o[4];
#pragma unroll
    for (int i = 0; i < 4; i++)
        o[i] = pack2bf(src[(size_t)(2*i) * 1024], src[(size_t)(2*i+1) * 1024]);
    *(uint4*)(out + (size_t)chunk * 512 + lane * 8) = make_uint4(o[0], o[1], o[2], o[3]);
}

// ---------- softmax: one block per row of 2048 bf16, in place ----------
__global__ void softmax_kernel(unsigned short* __restrict__ S) {
    const size_t row = blockIdx.x;
    unsigned short* p = S + row * 2048;
    const int tid = threadIdx.x;
    const int wave = tid >> 6, lane = tid & 63;

    uint4 raw = ((const uint4*)p)[tid];
    unsigned u[4] = {raw.x, raw.y, raw.z, raw.w};
    float x[8];
#pragma unroll
    for (int i = 0; i < 4; i++) {
        x[2*i]   = __uint_as_float(u[i] << 16);
        x[2*i+1] = __uint_as_float(u[i] & 0xffff0000u);
    }
    float m = x[0];
#pragma unroll
    for (int i = 1; i < 8; i++) m = fmaxf(m, x[i]);
#pragma unroll
    for (int off = 32; off >= 1; off >>= 1) m = fmaxf(m, __shfl_xor(m, off, 64));
    __shared__ float sm[4], ss[4];
    if (lane == 0) sm[wave] = m;
    __syncthreads();
    m = fmaxf(fmaxf(sm[0], sm[1]), fmaxf(sm[2], sm[3]));

    float e[8], s = 0.f;
#pragma unroll
    for (int i = 0; i < 8; i++) { e[i] = __expf(x[i] - m); s += e[i]; }
#pragma unroll
    for (int off = 32; off >= 1; off >>= 1) s += __shfl_xor(s, off, 64);
    if (lane == 0) ss[wave] = s;
    __syncthreads();
    s = ss[0] + ss[1] + ss[2] + ss[3];
    float inv = 1.0f / s;

    unsigned o[4];
#pragma unroll
    for (int i = 0; i < 4; i++)
        o[i] = pack2bf(e[2*i] * inv, e[2*i+1] * inv);
    ((uint4*)p)[tid] = make_uint4(o[0], o[1], o[2], o[3]);
}

// ---------- Pipelined NT GEMM with packed-B ----------
// C[m][n] = scale * sum_k A[m][k] * Bpk(n,k)  (+bias)
// 128x128 block tile, BK=64 stage, 4 waves 64x64, 16x16x32 bf16 MFMA.
// A: row-major -> double-buffered LDS (xor-swizzled, conflict-free, DMA staging).
// B: fragment-packed global chunks -> registers, ping-pong double buffer.
// Pipeline per stage: [vmcnt(0): stage-k data (issued last stage) done]
//                     [one barrier] [issue stage k+1 DMA + B-loads] [compute k]
// -> load latency hidden behind the ~600-cyc compute phase instead of exposed
//    between two barriers (R1-R6 structure).
// EPI: 0 = f32+bias direct; 1 = bf16 row-major (LDS-transpose, coalesced dwordx4);
//      2 = QKV triple: Q row-major bf16 / K fragment-packed / V packed-transposed.
template<int EPI>
__global__ __launch_bounds__(256)
void gemm_pk(const unsigned short* __restrict__ A, const unsigned short* __restrict__ Bpk,
             void* __restrict__ C, unsigned short* __restrict__ Ck, unsigned short* __restrict__ Cv,
             const float* __restrict__ bias,
             int lda, int ldc, int KS, int nk2, float scale,
             long long sA, long long sB, long long sC)
{
    constexpr int SMEM = (EPI == 2) ? 34816 : 32768;
    __shared__ __align__(16) char smem[SMEM];   // K-loop: 2 x 16 KB A stages

    const int tid  = threadIdx.x;
    const int lane = tid & 63;
    const int wave = tid >> 6;
    const int bz = blockIdx.z;
    A   += (size_t)bz * sA;
    Bpk += (size_t)bz * sB;
    const int bm = blockIdx.y * 128;
    const int bn = blockIdx.x * 128;

    // A staging: thread tid -> row tid>>2, chunk (tid&3)^((tid>>3)&3) within 64 B row
    const int srow = tid >> 2;
    const int scol = ((tid & 3) ^ ((tid >> 3) & 3)) * 8;
    const unsigned short* pa0 = A + (size_t)(bm + srow) * lda + scol;       // rows 0-63,  t0
    const unsigned short* pa1 = pa0 + 32;                                   // rows 0-63,  t1
    const unsigned short* pa2 = A + (size_t)(bm + 64 + srow) * lda + scol;  // rows 64-127,t0
    const unsigned short* pa3 = pa2 + 32;                                   // rows 64-127,t1

    const int wm = (wave & 1) * 64;
    const int wn = (wave >> 1) * 64;
    const int ln15 = lane & 15;
    const int quad = lane >> 4;
    const int fko = (quad ^ ((ln15 >> 1) & 3)) * 8;   // swizzled A-frag k-offset
    const int ldsoff = tid * 16;

    // B chunk pointers, one per j-fragment (advance 2 chunks = 1024 ushorts / stage)
    const unsigned short* pb[4];
#pragma unroll
    for (int j = 0; j < 4; j++)
        pb[j] = Bpk + (size_t)(((bn + wn + j*16) >> 4) * KS) * 512 + lane * 8;

    f32x4 acc[4][4];
#pragma unroll
    for (int i = 0; i < 4; i++)
#pragma unroll
        for (int j = 0; j < 4; j++) acc[i][j] = (f32x4){0.f, 0.f, 0.f, 0.f};

    // stage issue: DMA one 16 KB A stage into buffer p, load 8 B-frags into br
    auto stage_issue = [&](int p, bf16x8* br) {
        char* base = smem + p * 16384;
        gld_lds16(pa0, (unsigned short*)(base + ldsoff));          // t0 rows 0-63
        gld_lds16(pa2, (unsigned short*)(base + 4096  + ldsoff));  // t0 rows 64-127
        gld_lds16(pa1, (unsigned short*)(base + 8192  + ldsoff));  // t1 rows 0-63
        gld_lds16(pa3, (unsigned short*)(base + 12288 + ldsoff));  // t1 rows 64-127
        pa0 += 64; pa1 += 64; pa2 += 64; pa3 += 64;
#pragma unroll
        for (int j = 0; j < 4; j++) {
            br[j]     = *(const bf16x8*)(pb[j]);
            br[4 + j] = *(const bf16x8*)(pb[j] + 512);
            pb[j] += 1024;
        }
    };
    auto stage_compute = [&](int p, const bf16x8* br) {
        const unsigned short* As = (const unsigned short*)(smem + p * 16384);
#pragma unroll
        for (int t = 0; t < 2; t++) {
            bf16x8 af[4];
#pragma unroll
            for (int i = 0; i < 4; i++)
                af[i] = *(const bf16x8*)&As[t*4096 + (wm + i*16 + ln15) * 32 + fko];
#pragma unroll
            for (int i = 0; i < 4; i++)
#pragma unroll
                for (int j = 0; j < 4; j++)
                    acc[i][j] = __builtin_amdgcn_mfma_f32_16x16x32_bf16(
                        af[i], br[t*4 + j], acc[i][j], 0, 0, 0);
        }
    };

    bf16x8 b0[8], b1[8];
    stage_issue(0, b0);
    // nk2 is always even (16 or 32)
    for (int kt = 0; kt < nk2; kt += 2) {
        asm volatile("s_waitcnt vmcnt(0)" ::: "memory");   // stage kt ready
        __syncthreads();                                   // all waves past stage kt-1 reads
        stage_issue(1, b1);                                // prefetch stage kt+1
        stage_compute(0, b0);
        asm volatile("s_waitcnt vmcnt(0)" ::: "memory");   // stage kt+1 ready
        __syncthreads();
        if (kt + 2 < nk2) stage_issue(0, b0);              // prefetch stage kt+2
        stage_compute(1, b1);
    }

    // ---------------- epilogue ----------------
    // C/D layout: col = ln15, row = quad*4 + reg
    if (EPI == 0) {
        float bval[4];
#pragma unroll
        for (int j = 0; j < 4; j++) bval[j] = bias[bn + wn + j*16 + ln15];
        float* Co = (float*)C + (size_t)bz * sC;
#pragma unroll
        for (int i = 0; i < 4; i++) {
            int r0 = bm + wm + i*16 + quad*4;
#pragma unroll
            for (int j = 0; j < 4; j++) {
                int c = bn + wn + j*16 + ln15;
#pragma unroll
                for (int r = 0; r < 4; r++)
                    Co[(size_t)(r0 + r) * ldc + c] = acc[i][j][r] * scale + bval[j];
            }
        }
    } else if (EPI == 1) {
        __syncthreads();
        float* ep = (float*)(smem + wave * 4352);   // 16 x 68 f32
        unsigned short* Co = (unsigned short*)C + (size_t)bz * sC;
#pragma unroll
        for (int i = 0; i < 4; i++) {
#pragma unroll
            for (int j = 0; j < 4; j++)
#pragma unroll
                for (int r = 0; r < 4; r++)
                    ep[(quad*4 + r) * 68 + j*16 + ln15] = acc[i][j][r] * scale;
            __builtin_amdgcn_s_waitcnt(0);
#pragma unroll
            for (int p = 0; p < 2; p++) {
                int lrow = p*8 + (lane >> 3);
                int col0 = (lane & 7) * 8;
                float4 lo = *(const float4*)&ep[lrow * 68 + col0];
                float4 hi = *(const float4*)&ep[lrow * 68 + col0 + 4];
                uint4 o;
                o.x = pack2bf(lo.x, lo.y); o.y = pack2bf(lo.z, lo.w);
                o.z = pack2bf(hi.x, hi.y); o.w = pack2bf(hi.z, hi.w);
                *(uint4*)&Co[(size_t)(bm + wm + i*16 + lrow) * ldc + bn + wn + col0] = o;
            }
            __builtin_amdgcn_s_waitcnt(0);
        }
    } else {  // EPI == 2: Q row-major / K packed / V packed-transposed
        __syncthreads();
        float* ep = (float*)(smem + wave * 8704);   // 32 x 68 f32
        const int region = bn >> 10;                // 0=Q, 1=K, 2=V (block-uniform)
#pragma unroll
        for (int half = 0; half < 2; half++) {
#pragma unroll
            for (int ii = 0; ii < 2; ii++) {
                int i = half*2 + ii;
#pragma unroll
                for (int j = 0; j < 4; j++)
#pragma unroll
                    for (int r = 0; r < 4; r++)
                        ep[(ii*16 + quad*4 + r) * 68 + j*16 + ln15] = acc[i][j][r] * scale;
            }
            __builtin_amdgcn_s_waitcnt(0);
            const int mrow0 = bm + wm + half*32;    // global m of scratch row 0 (32-aligned)
            if (region == 0) {
                unsigned short* Q = (unsigned short*)C;
#pragma unroll
                for (int p = 0; p < 4; p++) {
                    int lrow = p*8 + (lane >> 3);
                    int col0 = (lane & 7) * 8;
                    float4 lo = *(const float4*)&ep[lrow * 68 + col0];
                    float4 hi = *(const float4*)&ep[lrow * 68 + col0 + 4];
                    uint4 o;
                    o.x = pack2bf(lo.x, lo.y); o.y = pack2bf(lo.z, lo.w);
                    o.z = pack2bf(hi.x, hi.y); o.w = pack2bf(hi.z, hi.w);
                    *(uint4*)&Q[(size_t)(mrow0 + lrow) * ldc + bn + wn + col0] = o;
                }
            } else if (region == 1) {
                // K chunk (m_tile, d32): lane(q,r) = K[mt*16+r][d32*32+q*8+e]
#pragma unroll
                for (int mt = 0; mt < 2; mt++)
#pragma unroll
                    for (int c = 0; c < 2; c++) {
                        float4 f0 = *(const float4*)&ep[(mt*16 + ln15) * 68 + c*32 + quad*8];
                        float4 f1 = *(const float4*)&ep[(mt*16 + ln15) * 68 + c*32 + quad*8 + 4];
                        uint4 o;
                        o.x = pack2bf(f0.x, f0.y); o.y = pack2bf(f0.z, f0.w);
                        o.z = pack2bf(f1.x, f1.y); o.w = pack2bf(f1.z, f1.w);
                        int cid = ((mrow0 + mt*16) >> 4) * 32 + ((bn - 1024 + wn + c*32) >> 5);
                        *(uint4*)(Ck + (size_t)cid * 512 + lane * 8) = o;
                    }
            } else {
                // V chunk (d_tile, s32): lane(q,r) = V[s32*32+q*8+e][dt*16+r] (transpose)
                int s32 = mrow0 >> 5;
#pragma unroll
                for (int dt = 0; dt < 4; dt++) {
                    float v[8];
#pragma unroll
                    for (int e = 0; e < 8; e++)
                        v[e] = ep[(quad*8 + e) * 68 + dt*16 + ln15];
                    uint4 o;
                    o.x = pack2bf(v[0], v[1]); o.y = pack2bf(v[2], v[3]);
                    o.z = pack2bf(v[4], v[5]); o.w = pack2bf(v[6], v[7]);
                    int cid = (((bn - 2048 + wn) >> 4) + dt) * 256 + s32;
                    *(uint4*)(Cv + (size_t)cid * 512 + lane * 8) = o;
                }
            }
            __builtin_amdgcn_s_waitcnt(0);
        }
    }
}

// ---------- launcher ----------
extern "C" void kernel_launch(void* const* d_in, const int* in_sizes, int n_in,
                              void* d_out, int out_size, void* d_ws, size_t ws_size,
                              hipStream_t stream) {
    const float* X  = (const float*)d_in[0];   // [4,2048,1024]
    const float* Wq = (const float*)d_in[1];   // [1024,1024]
    const float* Wk = (const float*)d_in[2];
    const float* Wv = (const float*)d_in[3];
    const float* Wo = (const float*)d_in[4];
    const float* bo = (const float*)d_in[5];   // [1024]
    float* out = (float*)d_out;

    size_t off = 0;
    auto alloc = [&](size_t bytes) {
        void* p = (char*)d_ws + off;
        off += (bytes + 255) & ~(size_t)255;
        return p;
    };
    unsigned short* Xbf  = (unsigned short*)alloc(8192ull * 1024 * 2);      // 16 MB (reused as AO)
    unsigned short* Wpk  = (unsigned short*)alloc(192ull * 32 * 512 * 2);   //  6 MB packed Wq|Wk|Wv
    unsigned short* Wopk = (unsigned short*)alloc(64ull * 32 * 512 * 2);    //  2 MB packed Wo
    unsigned short* Qrm  = (unsigned short*)alloc(8192ull * 1024 * 2);      // 16 MB row-major Q
    unsigned short* Kpk  = (unsigned short*)alloc(512ull * 32 * 512 * 2);   // 16 MB packed K
    unsigned short* Vpk  = (unsigned short*)alloc(64ull * 256 * 512 * 2);   // 16 MB packed V^T
    unsigned short* Sc   = (unsigned short*)alloc(4ull * 2048 * 2048 * 2);  // 32 MB scores/probs
    unsigned short* AO   = Xbf;   // X dead after G1

    cvt_kernel<<<(8192*1024/4 + 255)/256, 256, 0, stream>>>(X, Xbf, 8192*1024/4);
    wpack_kernel<<<512, 256, 0, stream>>>(Wq, Wpk);
    wpack_kernel<<<512, 256, 0, stream>>>(Wk, Wpk + 64*32*512);
    wpack_kernel<<<512, 256, 0, stream>>>(Wv, Wpk + 128*32*512);
    wpack_kernel<<<512, 256, 0, stream>>>(Wo, Wopk);

    // G1: [Q|K|V] = Xbf @ W^T   M=8192 N=3072 K=1024; Q row-major, K/V packed
    gemm_pk<2><<<dim3(3072/128, 8192/128, 1), 256, 0, stream>>>(
        Xbf, Wpk, Qrm, Kpk, Vpk, nullptr, 1024, 1024, 32, 16, 1.0f, 0, 0, 0);

    // G2: Sc = (Q @ K^T)/32 per batch   M=N=2048 K=1024
    gemm_pk<1><<<dim3(2048/128, 2048/128, 4), 256, 0, stream>>>(
        Qrm, Kpk, Sc, nullptr, nullptr, nullptr, 1024, 2048, 32, 16, 0.03125f,
        2048ll*1024, 128ll*32*512, 2048ll*2048);

    softmax_kernel<<<8192, 256, 0, stream>>>(Sc);

    // G3: AO = P @ V per batch   M=2048 N=1024 K=2048
    gemm_pk<1><<<dim3(1024/128, 2048/128, 4), 256, 0, stream>>>(
        Sc, Vpk, AO, nullptr, nullptr, nullptr, 2048, 1024, 256, 32, 1.0f,
        2048ll*2048, 64ll*512, 2048ll*1024);

    // G4: out = AO @ WoT^T + bo   M=8192 N=1024 K=1024, fp32 out
    gemm_pk<0><<<dim3(1024/128, 8192/128, 1), 256, 0, stream>>>(
        AO, Wopk, out, nullptr, nullptr, bo, 1024, 1024, 32, 16, 1.0f, 0, 0, 0);

    (void)n_in; (void)in_sizes; (void)out_size; (void)ws_size;
}